// Round 1
// baseline (643.028 us; speedup 1.0000x reference)
//
#include <hip/hip_runtime.h>

#define T_TOK 4096
#define DM 1024
#define DF 4096
#define NE 8
#define BM 128
#define BN 64
#define BK 64
#define RCAP 9216   // 8192 + 8*128 worst-case padding
#define MAXT 72     // RCAP / BM

typedef _Float16 f16x8 __attribute__((ext_vector_type(8)));
typedef float f32x4 __attribute__((ext_vector_type(4)));

__device__ __forceinline__ ushort f2h_bits(float f) {
    _Float16 h = (_Float16)f;
    return __builtin_bit_cast(unsigned short, h);
}

// ---------------- init: zero output, misc ints, row_tok=-1 ----------------
__global__ __launch_bounds__(256) void k_init(float* __restrict__ out,
                                              int* __restrict__ misc,
                                              int* __restrict__ row_tok) {
    int i = blockIdx.x * 256 + threadIdx.x;
    if (i < T_TOK * DM + 1) out[i] = 0.f;
    if (i < RCAP) row_tok[i] = -1;
    if (i < 256) misc[i] = 0;   // cnt[8], fill[8], poff[8], texp[72]
}

// ---------------- router: logits, softmax, top-2 ----------------
__global__ __launch_bounds__(64) void k_router(const float* __restrict__ x,
                                               const float* __restrict__ Wr,
                                               float* __restrict__ probs,
                                               int* __restrict__ topi,
                                               float* __restrict__ topw,
                                               int* __restrict__ cnt) {
    int t = blockIdx.x;
    int lane = threadIdx.x;
    const float* xr = x + (size_t)t * DM;
    float s[NE];
#pragma unroll
    for (int e = 0; e < NE; e++) s[e] = 0.f;
    for (int j = lane; j < DM; j += 64) {
        float xv = xr[j];
#pragma unroll
        for (int e = 0; e < NE; e++) s[e] += xv * Wr[e * DM + j];
    }
#pragma unroll
    for (int off = 32; off > 0; off >>= 1) {
#pragma unroll
        for (int e = 0; e < NE; e++) s[e] += __shfl_xor(s[e], off, 64);
    }
    if (lane == 0) {
        float mx = s[0];
#pragma unroll
        for (int e = 1; e < NE; e++) mx = fmaxf(mx, s[e]);
        float ex[NE], sum = 0.f;
#pragma unroll
        for (int e = 0; e < NE; e++) { ex[e] = expf(s[e] - mx); sum += ex[e]; }
        float inv = 1.f / sum;
        float p[NE];
#pragma unroll
        for (int e = 0; e < NE; e++) { p[e] = ex[e] * inv; probs[t * NE + e] = p[e]; }
        int i0 = 0;
#pragma unroll
        for (int e = 1; e < NE; e++) if (p[e] > p[i0]) i0 = e;
        int i1 = (i0 == 0) ? 1 : 0;
#pragma unroll
        for (int e = 0; e < NE; e++) if (e != i0 && p[e] > p[i1]) i1 = e;
        float w0 = p[i0], w1 = p[i1], winv = 1.f / (w0 + w1);
        topi[2 * t] = i0;     topw[2 * t] = w0 * winv;
        topi[2 * t + 1] = i1; topw[2 * t + 1] = w1 * winv;
        atomicAdd(&cnt[i0], 1);
        atomicAdd(&cnt[i1], 1);
    }
}

// ---------------- scan: importance (deterministic), aux loss, packed offsets ----------------
__global__ __launch_bounds__(256) void k_scan(const float* __restrict__ probs,
                                              const int* __restrict__ cnt,
                                              int* __restrict__ poff,
                                              int* __restrict__ texp,
                                              float* __restrict__ aux_out) {
    __shared__ float red[256 * NE];
    int tid = threadIdx.x;
    float part[NE];
#pragma unroll
    for (int e = 0; e < NE; e++) part[e] = 0.f;
    for (int t = tid; t < T_TOK; t += 256) {
#pragma unroll
        for (int e = 0; e < NE; e++) part[e] += probs[t * NE + e];
    }
#pragma unroll
    for (int e = 0; e < NE; e++) red[tid * NE + e] = part[e];
    __syncthreads();
    for (int s2 = 128; s2 > 0; s2 >>= 1) {
        if (tid < s2) {
#pragma unroll
            for (int e = 0; e < NE; e++) red[tid * NE + e] += red[(tid + s2) * NE + e];
        }
        __syncthreads();
    }
    if (tid == 0) {
        float al = 0.f;
#pragma unroll
        for (int e = 0; e < NE; e++) al += red[e] * (float)cnt[e];
        *aux_out = al * (8.0f / (16777216.0f + 1e-6f));
        int run = 0, tix = 0;
        for (int e = 0; e < NE; e++) {
            poff[e] = run;
            int nt = (cnt[e] + BM - 1) / BM;
            for (int i = 0; i < nt; i++) texp[tix++] = e;
            run += nt * BM;
        }
        // remaining texp entries stay 0 (zeroed in k_init)
    }
}

// ---------------- assign: token -> packed row slot ----------------
__global__ __launch_bounds__(256) void k_assign(const int* __restrict__ topi,
                                                const float* __restrict__ topw,
                                                const int* __restrict__ poff,
                                                int* __restrict__ fill,
                                                int* __restrict__ row_tok,
                                                float* __restrict__ row_w) {
    int t = blockIdx.x * 256 + threadIdx.x;
    if (t >= T_TOK) return;
#pragma unroll
    for (int k = 0; k < 2; k++) {
        int e = topi[2 * t + k];
        int pos = atomicAdd(&fill[e], 1);
        int r = poff[e] + pos;
        row_tok[r] = t;
        row_w[r] = topw[2 * t + k];
    }
}

// ---------------- gather: pack x rows (fp32 -> fp16) ----------------
__global__ __launch_bounds__(256) void k_gather(const float* __restrict__ x,
                                                const int* __restrict__ row_tok,
                                                ushort* __restrict__ xg) {
    int r = blockIdx.x;
    int tid = threadIdx.x;
    int tok = row_tok[r];
    ushort4 hv;
    if (tok >= 0) {
        float4 v = *(const float4*)(x + (size_t)tok * DM + tid * 4);
        hv.x = f2h_bits(v.x); hv.y = f2h_bits(v.y);
        hv.z = f2h_bits(v.z); hv.w = f2h_bits(v.w);
    } else {
        hv.x = 0; hv.y = 0; hv.z = 0; hv.w = 0;
    }
    *(ushort4*)(xg + (size_t)r * DM + tid * 4) = hv;
}

// ---------------- GEMM1: h = silu(xg @ W1^T) * (xg @ W3^T), fp16 out ----------------
__global__ __launch_bounds__(256) void k_gemm1(const ushort* __restrict__ xg,
                                               const float* __restrict__ W1,
                                               const float* __restrict__ W3,
                                               const int* __restrict__ texp,
                                               ushort* __restrict__ hbuf) {
    __shared__ char lA[BM * BK * 2];    // 16 KB, swizzled rows of 128 B
    __shared__ char lB1[BN * BK * 2];   // 8 KB
    __shared__ char lB3[BN * BK * 2];   // 8 KB
    int ct = blockIdx.x, rt = blockIdx.y;
    int e = texp[rt];
    const ushort* Ag = xg + (size_t)rt * BM * DM;
    const float* B1g = W1 + (size_t)e * DF * DM + (size_t)ct * BN * DM;
    const float* B3g = W3 + (size_t)e * DF * DM + (size_t)ct * BN * DM;
    int tid = threadIdx.x, lane = tid & 63, wv = tid >> 6;

    const f32x4 fz = {0.f, 0.f, 0.f, 0.f};
    f32x4 acc1[2][4], acc3[2][4];
#pragma unroll
    for (int m = 0; m < 2; m++)
#pragma unroll
        for (int n = 0; n < 4; n++) { acc1[m][n] = fz; acc3[m][n] = fz; }

    for (int k0 = 0; k0 < DM; k0 += BK) {
        // stage A (fp16, 16B per lane per pass)
#pragma unroll
        for (int p = 0; p < 4; p++) {
            int r = p * 32 + (tid >> 3);
            int kc = (tid & 7) * 8;
            uint4 v = *(const uint4*)(Ag + (size_t)r * DM + k0 + kc);
            *(uint4*)(lA + r * 128 + ((kc * 2) ^ ((r & 7) << 4))) = v;
        }
        // stage B1/B3 (fp32 -> fp16)
#pragma unroll
        for (int p = 0; p < 4; p++) {
            int n = p * 16 + (tid >> 4);
            int kc = (tid & 15) * 4;
            int boff = n * 128 + ((kc * 2) ^ ((n & 7) << 4));
            float4 v1 = *(const float4*)(B1g + (size_t)n * DM + k0 + kc);
            ushort4 h1; h1.x = f2h_bits(v1.x); h1.y = f2h_bits(v1.y);
            h1.z = f2h_bits(v1.z); h1.w = f2h_bits(v1.w);
            *(ushort4*)(lB1 + boff) = h1;
            float4 v3 = *(const float4*)(B3g + (size_t)n * DM + k0 + kc);
            ushort4 h3; h3.x = f2h_bits(v3.x); h3.y = f2h_bits(v3.y);
            h3.z = f2h_bits(v3.z); h3.w = f2h_bits(v3.w);
            *(ushort4*)(lB3 + boff) = h3;
        }
        __syncthreads();
#pragma unroll
        for (int ks = 0; ks < 2; ks++) {
            int kbyte = (ks * 32 + (lane >> 4) * 8) * 2;
            f16x8 af[2];
#pragma unroll
            for (int m = 0; m < 2; m++) {
                int r = wv * 32 + m * 16 + (lane & 15);
                af[m] = *(const f16x8*)(lA + r * 128 + (kbyte ^ ((r & 7) << 4)));
            }
#pragma unroll
            for (int n = 0; n < 4; n++) {
                int c = n * 16 + (lane & 15);
                int off = c * 128 + (kbyte ^ ((c & 7) << 4));
                f16x8 b1 = *(const f16x8*)(lB1 + off);
                f16x8 b3 = *(const f16x8*)(lB3 + off);
#pragma unroll
                for (int m = 0; m < 2; m++) {
                    acc1[m][n] = __builtin_amdgcn_mfma_f32_16x16x32_f16(af[m], b1, acc1[m][n], 0, 0, 0);
                    acc3[m][n] = __builtin_amdgcn_mfma_f32_16x16x32_f16(af[m], b3, acc3[m][n], 0, 0, 0);
                }
            }
        }
        __syncthreads();
    }
    // epilogue: silu(h1)*h3 -> hbuf (fp16)
    int rbase = rt * BM + wv * 32;
    int cbase = ct * BN;
#pragma unroll
    for (int m = 0; m < 2; m++) {
#pragma unroll
        for (int i = 0; i < 4; i++) {
            int row = rbase + m * 16 + (lane >> 4) * 4 + i;
            ushort* hrow = hbuf + (size_t)row * DF + cbase + (lane & 15);
#pragma unroll
            for (int n = 0; n < 4; n++) {
                float a1 = acc1[m][n][i];
                float a3 = acc3[m][n][i];
                float h = (a1 / (1.f + expf(-a1))) * a3;
                hrow[n * 16] = f2h_bits(h);
            }
        }
    }
}

// ---------------- GEMM2: y = h @ W2^T, weighted atomic scatter ----------------
__global__ __launch_bounds__(256) void k_gemm2(const ushort* __restrict__ hbuf,
                                               const float* __restrict__ W2,
                                               const int* __restrict__ texp,
                                               const int* __restrict__ row_tok,
                                               const float* __restrict__ row_w,
                                               float* __restrict__ out) {
    __shared__ char lA[BM * BK * 2];    // 16 KB
    __shared__ char lB[BN * BK * 2];    // 8 KB
    int ct = blockIdx.x, rt = blockIdx.y;
    int e = texp[rt];
    const ushort* Ag = hbuf + (size_t)rt * BM * DF;
    const float* Bg = W2 + (size_t)e * DM * DF + (size_t)ct * BN * DF;
    int tid = threadIdx.x, lane = tid & 63, wv = tid >> 6;

    const f32x4 fz = {0.f, 0.f, 0.f, 0.f};
    f32x4 acc[2][4];
#pragma unroll
    for (int m = 0; m < 2; m++)
#pragma unroll
        for (int n = 0; n < 4; n++) acc[m][n] = fz;

    for (int k0 = 0; k0 < DF; k0 += BK) {
#pragma unroll
        for (int p = 0; p < 4; p++) {
            int r = p * 32 + (tid >> 3);
            int kc = (tid & 7) * 8;
            uint4 v = *(const uint4*)(Ag + (size_t)r * DF + k0 + kc);
            *(uint4*)(lA + r * 128 + ((kc * 2) ^ ((r & 7) << 4))) = v;
        }
#pragma unroll
        for (int p = 0; p < 4; p++) {
            int n = p * 16 + (tid >> 4);
            int kc = (tid & 15) * 4;
            int boff = n * 128 + ((kc * 2) ^ ((n & 7) << 4));
            float4 v1 = *(const float4*)(Bg + (size_t)n * DF + k0 + kc);
            ushort4 h1; h1.x = f2h_bits(v1.x); h1.y = f2h_bits(v1.y);
            h1.z = f2h_bits(v1.z); h1.w = f2h_bits(v1.w);
            *(ushort4*)(lB + boff) = h1;
        }
        __syncthreads();
#pragma unroll
        for (int ks = 0; ks < 2; ks++) {
            int kbyte = (ks * 32 + (lane >> 4) * 8) * 2;
            f16x8 af[2];
#pragma unroll
            for (int m = 0; m < 2; m++) {
                int r = wv * 32 + m * 16 + (lane & 15);
                af[m] = *(const f16x8*)(lA + r * 128 + (kbyte ^ ((r & 7) << 4)));
            }
#pragma unroll
            for (int n = 0; n < 4; n++) {
                int c = n * 16 + (lane & 15);
                f16x8 b = *(const f16x8*)(lB + c * 128 + (kbyte ^ ((c & 7) << 4)));
#pragma unroll
                for (int m = 0; m < 2; m++) {
                    acc[m][n] = __builtin_amdgcn_mfma_f32_16x16x32_f16(af[m], b, acc[m][n], 0, 0, 0);
                }
            }
        }
        __syncthreads();
    }
    // epilogue: out[tok] += w * y   (exactly 2 adds per output element -> deterministic)
    int rbase = rt * BM + wv * 32;
    int cbase = ct * BN;
#pragma unroll
    for (int m = 0; m < 2; m++) {
#pragma unroll
        for (int i = 0; i < 4; i++) {
            int rr = rbase + m * 16 + (lane >> 4) * 4 + i;
            int tok = row_tok[rr];
            if (tok >= 0) {
                float w = row_w[rr];
                float* orow = out + (size_t)tok * DM + cbase + (lane & 15);
#pragma unroll
                for (int n = 0; n < 4; n++) {
                    atomicAdd(&orow[n * 16], w * acc[m][n][i]);
                }
            }
        }
    }
}

extern "C" void kernel_launch(void* const* d_in, const int* in_sizes, int n_in,
                              void* d_out, int out_size, void* d_ws, size_t ws_size,
                              hipStream_t stream) {
    (void)in_sizes; (void)n_in; (void)out_size; (void)ws_size;
    const float* x  = (const float*)d_in[0];
    const float* Wr = (const float*)d_in[1];
    const float* W1 = (const float*)d_in[2];
    const float* W2 = (const float*)d_in[3];
    const float* W3 = (const float*)d_in[4];
    float* out = (float*)d_out;
    char* ws = (char*)d_ws;

    int* misc = (int*)ws;            // [cnt 8][fill 8][poff 8][texp 72]
    int* cnt  = misc;
    int* fill = misc + 8;
    int* poff = misc + 16;
    int* texp = misc + 24;
    int*    topi    = (int*)(ws + 1024);
    float*  topw    = (float*)(ws + 33792);
    float*  probs   = (float*)(ws + 66560);
    int*    row_tok = (int*)(ws + 197632);
    float*  row_w   = (float*)(ws + 234496);
    ushort* xg      = (ushort*)(ws + 271360);     // RCAP x 1024 fp16  (18.9 MB)
    ushort* hbuf    = (ushort*)(ws + 19145728);   // RCAP x 4096 fp16  (75.5 MB)

    k_init<<<(T_TOK * DM + 1 + 255) / 256, 256, 0, stream>>>(out, misc, row_tok);
    k_router<<<T_TOK, 64, 0, stream>>>(x, Wr, probs, topi, topw, cnt);
    k_scan<<<1, 256, 0, stream>>>(probs, cnt, poff, texp, out + (size_t)T_TOK * DM);
    k_assign<<<(T_TOK + 255) / 256, 256, 0, stream>>>(topi, topw, poff, fill, row_tok, row_w);
    k_gather<<<RCAP, 256, 0, stream>>>(x, row_tok, xg);
    dim3 g1(DF / BN, MAXT);
    k_gemm1<<<g1, 256, 0, stream>>>(xg, W1, W3, texp, hbuf);
    dim3 g2(DM / BN, MAXT);
    k_gemm2<<<g2, 256, 0, stream>>>(hbuf, W2, texp, row_tok, row_w, out);
}